// Round 6
// baseline (144.385 us; speedup 1.0000x reference)
//
#include <hip/hip_runtime.h>
#include <hip/hip_bf16.h>

typedef unsigned short u16;
typedef unsigned int u32;
typedef __attribute__((ext_vector_type(8))) short bf16x8;   // 8 bf16 = 4 VGPRs (MFMA A/B frag)
typedef __attribute__((ext_vector_type(4))) float f32x4;    // MFMA C/D frag

#define BB 4
#define NN 2048
#define DD 256
#define HH 8
#define LAMBDA 0.2550351f   // log2(e)/sqrt(32): folded into Q so sigmoid uses native exp2
#define BIGM 1024.0f

__device__ inline u16 bfu(float f) {
  __hip_bfloat16 h = __float2bfloat16(f);
  return *reinterpret_cast<u16*>(&h);
}
__device__ inline bf16x8 asfrag(uint4 v) { return __builtin_bit_cast(bf16x8, v); }

// ---------------- merged prep: x=qdt+boxes, mask->u8, weights ----------------
__global__ __launch_bounds__(256) void prep_kernel(
    const float* __restrict__ qdt, const float* __restrict__ boxes,
    const int* __restrict__ mask,
    const float* __restrict__ Wq, const float* __restrict__ Wk, const float* __restrict__ Wv,
    const float* __restrict__ Wo, const float* __restrict__ W1, const float* __restrict__ W2,
    const float* __restrict__ bq, const float* __restrict__ bk, const float* __restrict__ bv,
    float* __restrict__ x, u16* __restrict__ xb, unsigned char* __restrict__ m8,
    u16* __restrict__ wqkvT, u16* __restrict__ woT, u16* __restrict__ w1T, u16* __restrict__ w2T,
    float* __restrict__ bqkv) {
  const int bid = blockIdx.x, t = threadIdx.x;
  if (bid < 2048) {                       // x = qdt + boxes (fp32 + bf16)
    int i = bid * 256 + t;
    float4 a = ((const float4*)qdt)[i];
    float4 b = ((const float4*)boxes)[i];
    float4 v = make_float4(a.x + b.x, a.y + b.y, a.z + b.z, a.w + b.w);
    ((float4*)x)[i] = v;
    ((ushort4*)xb)[i] = make_ushort4(bfu(v.x), bfu(v.y), bfu(v.z), bfu(v.w));
  } else if (bid < 6144) {                // mask int -> u8 0/1
    int i = (bid - 2048) * 256 + t;
    int4 m = ((const int4*)mask)[i];
    ((uchar4*)m8)[i] = make_uchar4((unsigned char)m.x, (unsigned char)m.y,
                                   (unsigned char)m.z, (unsigned char)m.w);
  } else {                                // weight transposes + qkv bias concat
    int i = (bid - 6144) * 256 + t;
    if (i < 196608) {
      int n = i >> 8, k = i & 255;
      const float* src = (n < 256) ? Wq : (n < 512 ? Wk : Wv);
      wqkvT[i] = bfu(src[k * 256 + (n & 255)]);
    } else if (i < 262144) {
      int j = i - 196608; int n = j >> 8, k = j & 255;
      woT[j] = bfu(Wo[k * 256 + n]);
    } else if (i < 327680) {
      int j = i - 262144; int n = j >> 8, k = j & 255;
      w1T[j] = bfu(W1[k * 256 + n]);
    } else if (i < 393216) {
      int j = i - 327680; int n = j >> 8, k = j & 255;
      w2T[j] = bfu(W2[k * 256 + n]);
    } else if (i < 393984) {
      int n = i - 393216;
      bqkv[n] = (n < 256) ? bq[n] : (n < 512 ? bk[n - 256] : bv[n - 512]);
    }
  }
}

// ============ shared GEMM body: C = A[M,256] @ Bt[N,256]^T, 64x64 tile ============
#define GEMM_BODY()                                                              \
  __shared__ u16 At[64][264];                                                    \
  __shared__ u16 Bs[64][264];                                                    \
  const int m0 = blockIdx.x * 64;                                                \
  const int n0 = blockIdx.y * 64;                                                \
  const int t = threadIdx.x;                                                     \
  {                                                                              \
    const int row = t >> 2, cb = (t & 3) * 64;                                   \
    const u16* ga = A  + (size_t)(m0 + row) * 256 + cb;                          \
    const u16* gb = Bt + (size_t)(n0 + row) * 256 + cb;                          \
    _Pragma("unroll")                                                            \
    for (int i = 0; i < 8; ++i) {                                                \
      *(int4*)&At[row][cb + i * 8] = *(const int4*)(ga + i * 8);                 \
      *(int4*)&Bs[row][cb + i * 8] = *(const int4*)(gb + i * 8);                 \
    }                                                                            \
  }                                                                              \
  __syncthreads();                                                               \
  const int w = t >> 6, l = t & 63, g = l >> 4, c = l & 15;                      \
  f32x4 acc[4] = {};                                                             \
  _Pragma("unroll")                                                              \
  for (int kk = 0; kk < 256; kk += 32) {                                         \
    bf16x8 af = *(const bf16x8*)&At[w * 16 + c][kk + g * 8];                     \
    _Pragma("unroll")                                                            \
    for (int j = 0; j < 4; ++j) {                                                \
      bf16x8 bfr = *(const bf16x8*)&Bs[j * 16 + c][kk + g * 8];                  \
      acc[j] = __builtin_amdgcn_mfma_f32_16x16x32_bf16(af, bfr, acc[j], 0, 0, 0);\
    }                                                                            \
  }

// QKV (q,k part): q scaled by LAMBDA -> [8192][256]; k -> [B][H][2048][32]
__global__ __launch_bounds__(256) void gemm_qk_kernel(
    const u16* __restrict__ A, const u16* __restrict__ Bt, const float* __restrict__ bias,
    u16* __restrict__ qout, u16* __restrict__ kout) {
  GEMM_BODY()
  if (n0 < 256) {
#pragma unroll
    for (int j = 0; j < 4; ++j)
#pragma unroll
      for (int r = 0; r < 4; ++r) {
        int m = m0 + w * 16 + g * 4 + r, n = n0 + j * 16 + c;
        qout[(size_t)m * 256 + n] = bfu((acc[j][r] + bias[n]) * LAMBDA);
      }
  } else {
#pragma unroll
    for (int j = 0; j < 4; ++j)
#pragma unroll
      for (int r = 0; r < 4; ++r) {
        int m = m0 + w * 16 + g * 4 + r, n = n0 + j * 16 + c;
        int ch = n - 256;
        kout[(size_t)((m >> 11) * 8 + (ch >> 5)) * 65536 + (size_t)(m & 2047) * 32 + (ch & 31)]
            = bfu(acc[j][r] + bias[n]);
      }
  }
}

// V^T: A = WvT[256][256], Bt = xb[8192][256] -> vT[256][8192], bias by m(channel)
__global__ __launch_bounds__(256) void gemm_vt_kernel(
    const u16* __restrict__ A, const u16* __restrict__ Bt, const float* __restrict__ bias,
    u16* __restrict__ vtout) {
  GEMM_BODY()
#pragma unroll
  for (int j = 0; j < 4; ++j)
#pragma unroll
    for (int r = 0; r < 4; ++r) {
      int m = m0 + w * 16 + g * 4 + r;   // channel
      int n = n0 + j * 16 + c;           // token
      vtout[(size_t)m * 8192 + n] = bfu(acc[j][r] + bias[m]);
    }
}

// MODE 1: relu + bf16 store. MODE 2: fp32 store of acc+bias+res.
template<int MODE>
__global__ __launch_bounds__(256) void gemm256_kernel(
    const u16* __restrict__ A, const u16* __restrict__ Bt,
    const float* __restrict__ bias, const float* res,
    void* out, int ldout) {
  GEMM_BODY()
#pragma unroll
  for (int j = 0; j < 4; ++j)
#pragma unroll
    for (int r = 0; r < 4; ++r) {
      int m = m0 + w * 16 + g * 4 + r;
      int n = n0 + j * 16 + c;
      float v = acc[j][r] + bias[n];
      size_t oi = (size_t)m * ldout + n;
      if (MODE == 1) {
        ((u16*)out)[oi] = bfu(v > 0.f ? v : 0.f);
      } else {
        ((float*)out)[oi] = v + res[(size_t)m * 256 + n];
      }
    }
}

// ---------------- fused sigmoid-gated attention (BISECT build) ----------------
// = round-1 PASSING kernel (Mlds rotation staging + BIGM arithmetic gate + exp2f)
//   with exactly ONE changed element: padded-u32 K/V/P LDS geometry (no XOR).
// block = (b, h, 64 q); 4 waves x 16 q. kv tiles of 64, dbuf, 1 barrier/tile.
__global__ __launch_bounds__(256) void attn_kernel(
    const u16* __restrict__ qb,            // [8192][256] bf16, LAMBDA-scaled
    const u16* __restrict__ kb,            // [B][H][2048][32] bf16
    const u16* __restrict__ vtb,           // [256][8192] bf16 (V^T)
    const unsigned char* __restrict__ m8,  // [2048][2048] 0/1
    u16* __restrict__ ob) {                // [8192][256] bf16
  __shared__ u32 Klds[2][64][20];          // 16 data u32 + 4 pad (row 80 B)
  __shared__ u32 Vlds[2][32][36];          // 32 data u32 + 4 pad (row 144 B)
  __shared__ unsigned char Mlds[2][64][64];// mask tile, byte-rotated rows
  __shared__ u32 Plds[4][16][36];          // 32 data u32 + 4 pad, per-wave

  const int bid = blockIdx.x;
  const int qt = bid & 31, h = (bid >> 5) & 7, b = bid >> 8;
  const int q0 = qt * 64;
  const int t = threadIdx.x, w = t >> 6, l = t & 63, g = l >> 4, c = l & 15;

  // Q as B-frag (col = q-token = c, k-dim = dh = 8g+j), held in regs
  const bf16x8 qf = asfrag(*(const uint4*)(qb + (size_t)(b * NN + q0 + 16 * w + c) * 256 + h * 32 + 8 * g));
  f32x4 oacc[2] = {};

  const int srowK = t >> 2, ssegK = t & 3;       // K & mask tiles: 64 rows
  const int srowV = t >> 3, ssegV = t & 7;       // V^T tile: 32 rows x 8 16B segs
  const u16* kg = kb + (size_t)(b * 8 + h) * 65536 + srowK * 32 + ssegK * 8;
  const u16* vg = vtb + (size_t)(h * 32 + srowV) * 8192 + (size_t)b * NN + ssegV * 8;
  const unsigned char* mg = m8 + (size_t)(q0 + srowK) * NN + ssegK * 16;

  const int mb0 = (16 * ssegK + 8 * (srowK & 7)) & 63;   // byte-rotation by 8*(row&7)
  const int mb1 = (mb0 + 8) & 63;

  // prologue: stage tile 0
  uint4 krg = *(const uint4*)kg;
  uint4 vrg = *(const uint4*)vg;
  uint4 mrg = *(const uint4*)mg;
  *(uint4*)&Klds[0][srowK][ssegK * 4] = krg;
  *(uint4*)&Vlds[0][srowV][ssegV * 4] = vrg;
  *(uint2*)&Mlds[0][srowK][mb0] = make_uint2(mrg.x, mrg.y);
  *(uint2*)&Mlds[0][srowK][mb1] = make_uint2(mrg.z, mrg.w);
  __syncthreads();

  const f32x4 zf = {0.f, 0.f, 0.f, 0.f};
  u32* Pw = &Plds[w][0][0];          // wave-private, row stride 36 u32

  for (int it = 0; it < 32; ++it) {
    const int cur = it & 1;
    if (it < 31) {                   // prefetch tile it+1 (global; hides under compute)
      const int kt = (it + 1) * 64;
      krg = *(const uint4*)(kg + (size_t)kt * 32);
      vrg = *(const uint4*)(vg + kt);
      mrg = *(const uint4*)(mg + kt);
    }
    // S^T = mfma(K, Q): lane(g,c): q = q0+16w+c, k = kt + 16tt + 4g + r
#pragma unroll
    for (int tt = 0; tt < 4; ++tt) {
      bf16x8 kf = asfrag(*(const uint4*)&Klds[cur][16 * tt + c][4 * g]);
      f32x4 s = __builtin_amdgcn_mfma_f32_16x16x32_bf16(kf, qf, zf, 0, 0, 0);
      u32 mdw = *(const u32*)&Mlds[cur][16 * w + c][(16 * tt + 4 * g + 8 * (c & 7)) & 63];
      float mf0 = (float)(mdw & 0xffu);
      float mf1 = (float)((mdw >> 8) & 0xffu);
      float mf2 = (float)((mdw >> 16) & 0xffu);
      float mf3 = (float)(mdw >> 24);
      // masked: s-BIG -> sigmoid == rcp(inf) == 0 exactly
      float s0 = fmaf(mf0, BIGM, s[0] - BIGM);
      float s1 = fmaf(mf1, BIGM, s[1] - BIGM);
      float s2 = fmaf(mf2, BIGM, s[2] - BIGM);
      float s3 = fmaf(mf3, BIGM, s[3] - BIGM);
      float p0 = __builtin_amdgcn_rcpf(1.f + exp2f(-s0));
      float p1 = __builtin_amdgcn_rcpf(1.f + exp2f(-s1));
      float p2 = __builtin_amdgcn_rcpf(1.f + exp2f(-s2));
      float p3 = __builtin_amdgcn_rcpf(1.f + exp2f(-s3));
      u32 w0, w1;
      asm("v_cvt_pk_bf16_f32 %0, %1, %2" : "=v"(w0) : "v"(p0), "v"(p1));
      asm("v_cvt_pk_bf16_f32 %0, %1, %2" : "=v"(w1) : "v"(p2), "v"(p3));
      *(uint2*)&Pw[c * 36 + 8 * tt + 2 * g] = make_uint2(w0, w1);
    }
    // hard fence on the wave-private P path (semantically neutral, rule-18 safe)
    asm volatile("s_waitcnt lgkmcnt(0)" ::: "memory");
    __builtin_amdgcn_sched_barrier(0);
    // PV: O += P @ V
#pragma unroll
    for (int kk = 0; kk < 2; ++kk) {
      bf16x8 pf = asfrag(*(const uint4*)&Pw[c * 36 + 16 * kk + 4 * g]);
#pragma unroll
      for (int d0 = 0; d0 < 2; ++d0) {
        bf16x8 vf = asfrag(*(const uint4*)&Vlds[cur][16 * d0 + c][16 * kk + 4 * g]);
        oacc[d0] = __builtin_amdgcn_mfma_f32_16x16x32_bf16(pf, vf, oacc[d0], 0, 0, 0);
      }
    }
    if (it < 31) {
      *(uint4*)&Klds[cur ^ 1][srowK][ssegK * 4] = krg;
      *(uint4*)&Vlds[cur ^ 1][srowV][ssegV * 4] = vrg;
      *(uint2*)&Mlds[cur ^ 1][srowK][mb0] = make_uint2(mrg.x, mrg.y);
      *(uint2*)&Mlds[cur ^ 1][srowK][mb1] = make_uint2(mrg.z, mrg.w);
    }
    __syncthreads();
  }

  const size_t obase = (size_t)(b * NN + q0 + 16 * w) * 256 + h * 32;
#pragma unroll
  for (int d0 = 0; d0 < 2; ++d0)
#pragma unroll
    for (int r = 0; r < 4; ++r)
      ob[obase + (size_t)(4 * g + r) * 256 + 16 * d0 + c] = bfu(oacc[d0][r]);
}

// ---------------- LayerNorm: wave per row ----------------
template<int WB>
__global__ __launch_bounds__(256) void ln_kernel(const float* y,
    const float* __restrict__ gam, const float* __restrict__ bet,
    float* outf, u16* outb) {
  const int row = blockIdx.x * 4 + (threadIdx.x >> 6);
  const int l = threadIdx.x & 63;
  const float4 v = ((const float4*)(y + (size_t)row * DD))[l];
  float s1 = v.x + v.y + v.z + v.w;
  float s2 = v.x * v.x + v.y * v.y + v.z * v.z + v.w * v.w;
#pragma unroll
  for (int off = 1; off < 64; off <<= 1) {
    s1 += __shfl_xor(s1, off);
    s2 += __shfl_xor(s2, off);
  }
  const float mean = s1 * (1.f / DD);
  const float var = s2 * (1.f / DD) - mean * mean;
  const float inv = rsqrtf(var + 1e-5f);
  const float4 gg = ((const float4*)gam)[l];
  const float4 bb = ((const float4*)bet)[l];
  float o0 = (v.x - mean) * inv * gg.x + bb.x;
  float o1 = (v.y - mean) * inv * gg.y + bb.y;
  float o2 = (v.z - mean) * inv * gg.z + bb.z;
  float o3 = (v.w - mean) * inv * gg.w + bb.w;
  ((float4*)(outf + (size_t)row * DD))[l] = make_float4(o0, o1, o2, o3);
  if (WB) {
    ((ushort4*)(outb + (size_t)row * DD))[l] = make_ushort4(bfu(o0), bfu(o1), bfu(o2), bfu(o3));
  }
}

extern "C" void kernel_launch(void* const* d_in, const int* in_sizes, int n_in,
                              void* d_out, int out_size, void* d_ws, size_t ws_size,
                              hipStream_t stream) {
  const float* qdt   = (const float*)d_in[0];
  const float* boxes = (const float*)d_in[1];
  const int*   mask  = (const int*)d_in[2];
  const float* Wq = (const float*)d_in[3];
  const float* bq = (const float*)d_in[4];
  const float* Wk = (const float*)d_in[5];
  const float* bk = (const float*)d_in[6];
  const float* Wv = (const float*)d_in[7];
  const float* bv = (const float*)d_in[8];
  const float* Wo = (const float*)d_in[9];
  const float* bo = (const float*)d_in[10];
  const float* W1 = (const float*)d_in[11];
  const float* b1 = (const float*)d_in[12];
  const float* W2 = (const float*)d_in[13];
  const float* b2 = (const float*)d_in[14];
  const float* g1  = (const float*)d_in[15];
  const float* be1 = (const float*)d_in[16];
  const float* g2  = (const float*)d_in[17];
  const float* be2 = (const float*)d_in[18];

  char* ws = (char*)d_ws;
  float* x     = (float*)(ws + 0);          // [8192,256] f32 (later reused as y2)
  u16*   xb    = (u16*)  (ws + 8388608);
  u16*   qbuf  = (u16*)  (ws + 12582912);   // q, LAMBDA-scaled
  u16*   kbuf  = (u16*)  (ws + 16777216);   // [B][H][2048][32]
  u16*   vtbuf = (u16*)  (ws + 20971520);   // [256][8192]
  u16*   obuf  = (u16*)  (ws + 25165824);
  float* y1    = (float*)(ws + 29360128);
  u16*   t1b   = (u16*)  (ws + 37748736);
  u16*   f1b   = (u16*)  (ws + 41943040);
  u16*   wqkvT = (u16*)  (ws + 46137344);   // [768,256]
  u16*   woT   = (u16*)  (ws + 46530560);
  u16*   w1T   = (u16*)  (ws + 46661632);
  u16*   w2T   = (u16*)  (ws + 46792704);
  float* bqkv  = (float*)(ws + 46923776);
  unsigned char* m8 = (unsigned char*)(ws + 46926848);  // [2048,2048] u8 (round-1 home, no overlay)

  // merged prep: x/xb (2048 blk) + mask->m8 (4096 blk) + weights (1539 blk)
  prep_kernel<<<7683, 256, 0, stream>>>(qdt, boxes, mask, Wq, Wk, Wv, Wo, W1, W2,
                                        bq, bk, bv, x, xb, m8,
                                        wqkvT, woT, w1T, w2T, bqkv);
  // Q (scaled) + K (relayout): [8192,256] x [256,512]
  gemm_qk_kernel<<<dim3(128, 8), 256, 0, stream>>>(xb, wqkvT, bqkv, qbuf, kbuf);
  // V^T: [256,256] x [256,8192]^T
  gemm_vt_kernel<<<dim3(4, 128), 256, 0, stream>>>(wqkvT + 512 * 256, xb, bqkv + 512, vtbuf);
  // attention
  attn_kernel<<<1024, 256, 0, stream>>>(qbuf, kbuf, vtbuf, m8, obuf);
  // attn_out = O@Wo + bo + x  (fp32)
  gemm256_kernel<2><<<dim3(128, 4), 256, 0, stream>>>(obuf, woT, bo, x, y1, 256);
  // LN1 in-place + bf16 copy
  ln_kernel<1><<<2048, 256, 0, stream>>>(y1, g1, be1, y1, t1b);
  // FF1 + relu
  gemm256_kernel<1><<<dim3(128, 4), 256, 0, stream>>>(t1b, w1T, b1, nullptr, f1b, 256);
  // FF2 + b2 + t1 -> reuse x
  gemm256_kernel<2><<<dim3(128, 4), 256, 0, stream>>>(f1b, w2T, b2, y1, x, 256);
  // LN2 -> d_out
  ln_kernel<0><<<2048, 256, 0, stream>>>(x, g2, be2, (float*)d_out, nullptr);
}

// Round 7
// 127.278 us; speedup vs baseline: 1.1344x; 1.1344x over previous
//
#include <hip/hip_runtime.h>
#include <hip/hip_bf16.h>

typedef unsigned short u16;
typedef unsigned int u32;
typedef __attribute__((ext_vector_type(8))) short bf16x8;   // 8 bf16 = 4 VGPRs (MFMA A/B frag)
typedef __attribute__((ext_vector_type(4))) float f32x4;    // MFMA C/D frag

#define BB 4
#define NN 2048
#define DD 256
#define HH 8
#define LAMBDA 0.17677669529f   // 1/sqrt(32), natural-log units (__expf supplies log2e)

__device__ inline u16 bfu(float f) {
  __hip_bfloat16 h = __float2bfloat16(f);
  return *reinterpret_cast<u16*>(&h);
}
__device__ inline bf16x8 asfrag(uint4 v) { return __builtin_bit_cast(bf16x8, v); }

// ---------------- merged prep: x=qdt+boxes, mask->u8, weights ----------------
__global__ __launch_bounds__(256) void prep_kernel(
    const float* __restrict__ qdt, const float* __restrict__ boxes,
    const int* __restrict__ mask,
    const float* __restrict__ Wq, const float* __restrict__ Wk, const float* __restrict__ Wv,
    const float* __restrict__ Wo, const float* __restrict__ W1, const float* __restrict__ W2,
    const float* __restrict__ bq, const float* __restrict__ bk, const float* __restrict__ bv,
    float* __restrict__ x, u16* __restrict__ xb, unsigned char* __restrict__ m8,
    u16* __restrict__ wqkvT, u16* __restrict__ woT, u16* __restrict__ w1T, u16* __restrict__ w2T,
    float* __restrict__ bqkv) {
  const int bid = blockIdx.x, t = threadIdx.x;
  if (bid < 2048) {                       // x = qdt + boxes (fp32 + bf16)
    int i = bid * 256 + t;
    float4 a = ((const float4*)qdt)[i];
    float4 b = ((const float4*)boxes)[i];
    float4 v = make_float4(a.x + b.x, a.y + b.y, a.z + b.z, a.w + b.w);
    ((float4*)x)[i] = v;
    ((ushort4*)xb)[i] = make_ushort4(bfu(v.x), bfu(v.y), bfu(v.z), bfu(v.w));
  } else if (bid < 6144) {                // mask int -> u8 0/1
    int i = (bid - 2048) * 256 + t;
    int4 m = ((const int4*)mask)[i];
    ((uchar4*)m8)[i] = make_uchar4((unsigned char)m.x, (unsigned char)m.y,
                                   (unsigned char)m.z, (unsigned char)m.w);
  } else {                                // weight transposes + qkv bias concat
    int i = (bid - 6144) * 256 + t;
    if (i < 196608) {
      int n = i >> 8, k = i & 255;
      const float* src = (n < 256) ? Wq : (n < 512 ? Wk : Wv);
      wqkvT[i] = bfu(src[k * 256 + (n & 255)]);
    } else if (i < 262144) {
      int j = i - 196608; int n = j >> 8, k = j & 255;
      woT[j] = bfu(Wo[k * 256 + n]);
    } else if (i < 327680) {
      int j = i - 262144; int n = j >> 8, k = j & 255;
      w1T[j] = bfu(W1[k * 256 + n]);
    } else if (i < 393216) {
      int j = i - 327680; int n = j >> 8, k = j & 255;
      w2T[j] = bfu(W2[k * 256 + n]);
    } else if (i < 393984) {
      int n = i - 393216;
      bqkv[n] = (n < 256) ? bq[n] : (n < 512 ? bk[n - 256] : bv[n - 512]);
    }
  }
}

// ============ shared GEMM body: C = A[M,256] @ Bt[N,256]^T, 64x64 tile ============
#define GEMM_BODY()                                                              \
  __shared__ u16 At[64][264];                                                    \
  __shared__ u16 Bs[64][264];                                                    \
  const int m0 = blockIdx.x * 64;                                                \
  const int n0 = blockIdx.y * 64;                                                \
  const int t = threadIdx.x;                                                     \
  {                                                                              \
    const int row = t >> 2, cb = (t & 3) * 64;                                   \
    const u16* ga = A  + (size_t)(m0 + row) * 256 + cb;                          \
    const u16* gb = Bt + (size_t)(n0 + row) * 256 + cb;                          \
    _Pragma("unroll")                                                            \
    for (int i = 0; i < 8; ++i) {                                                \
      *(int4*)&At[row][cb + i * 8] = *(const int4*)(ga + i * 8);                 \
      *(int4*)&Bs[row][cb + i * 8] = *(const int4*)(gb + i * 8);                 \
    }                                                                            \
  }                                                                              \
  __syncthreads();                                                               \
  const int w = t >> 6, l = t & 63, g = l >> 4, c = l & 15;                      \
  f32x4 acc[4] = {};                                                             \
  _Pragma("unroll")                                                              \
  for (int kk = 0; kk < 256; kk += 32) {                                         \
    bf16x8 af = *(const bf16x8*)&At[w * 16 + c][kk + g * 8];                     \
    _Pragma("unroll")                                                            \
    for (int j = 0; j < 4; ++j) {                                                \
      bf16x8 bfr = *(const bf16x8*)&Bs[j * 16 + c][kk + g * 8];                  \
      acc[j] = __builtin_amdgcn_mfma_f32_16x16x32_bf16(af, bfr, acc[j], 0, 0, 0);\
    }                                                                            \
  }

// QKV (q,k part): q scaled by LAMBDA -> [8192][256]; k -> [B][H][2048][32]
__global__ __launch_bounds__(256) void gemm_qk_kernel(
    const u16* __restrict__ A, const u16* __restrict__ Bt, const float* __restrict__ bias,
    u16* __restrict__ qout, u16* __restrict__ kout) {
  GEMM_BODY()
  if (n0 < 256) {
#pragma unroll
    for (int j = 0; j < 4; ++j)
#pragma unroll
      for (int r = 0; r < 4; ++r) {
        int m = m0 + w * 16 + g * 4 + r, n = n0 + j * 16 + c;
        qout[(size_t)m * 256 + n] = bfu((acc[j][r] + bias[n]) * LAMBDA);
      }
  } else {
#pragma unroll
    for (int j = 0; j < 4; ++j)
#pragma unroll
      for (int r = 0; r < 4; ++r) {
        int m = m0 + w * 16 + g * 4 + r, n = n0 + j * 16 + c;
        int ch = n - 256;
        kout[(size_t)((m >> 11) * 8 + (ch >> 5)) * 65536 + (size_t)(m & 2047) * 32 + (ch & 31)]
            = bfu(acc[j][r] + bias[n]);
      }
  }
}

// V^T: A = WvT[256][256], Bt = xb[8192][256] -> vT[256][8192], bias by m(channel)
__global__ __launch_bounds__(256) void gemm_vt_kernel(
    const u16* __restrict__ A, const u16* __restrict__ Bt, const float* __restrict__ bias,
    u16* __restrict__ vtout) {
  GEMM_BODY()
#pragma unroll
  for (int j = 0; j < 4; ++j)
#pragma unroll
    for (int r = 0; r < 4; ++r) {
      int m = m0 + w * 16 + g * 4 + r;   // channel
      int n = n0 + j * 16 + c;           // token
      vtout[(size_t)m * 8192 + n] = bfu(acc[j][r] + bias[m]);
    }
}

// MODE 1: relu + bf16 store. MODE 2: fp32 store of acc+bias+res.
template<int MODE>
__global__ __launch_bounds__(256) void gemm256_kernel(
    const u16* __restrict__ A, const u16* __restrict__ Bt,
    const float* __restrict__ bias, const float* res,
    void* out, int ldout) {
  GEMM_BODY()
#pragma unroll
  for (int j = 0; j < 4; ++j)
#pragma unroll
    for (int r = 0; r < 4; ++r) {
      int m = m0 + w * 16 + g * 4 + r;
      int n = n0 + j * 16 + c;
      float v = acc[j][r] + bias[n];
      size_t oi = (size_t)m * ldout + n;
      if (MODE == 1) {
        ((u16*)out)[oi] = bfu(v > 0.f ? v : 0.f);
      } else {
        ((float*)out)[oi] = v + res[(size_t)m * 256 + n];
      }
    }
}

// ---------------- fused sigmoid-gated attention ----------------
// = round-6 PASSING build with ONE change: sigmoid path restored to round-1's
//   proven formula  p = mv * rcp(1 + __expf(-s))  (2-inst __expf vs ~5-inst
//   libm exp2f + fma-BIGM gating). LAMBDA folded into Q is now 1/sqrt(32).
// block = (b, h, 64 q); 4 waves x 16 q. kv tiles of 64, dbuf, 1 barrier/tile.
__global__ __launch_bounds__(256) void attn_kernel(
    const u16* __restrict__ qb,            // [8192][256] bf16, LAMBDA-scaled
    const u16* __restrict__ kb,            // [B][H][2048][32] bf16
    const u16* __restrict__ vtb,           // [256][8192] bf16 (V^T)
    const unsigned char* __restrict__ m8,  // [2048][2048] 0/1
    u16* __restrict__ ob) {                // [8192][256] bf16
  __shared__ u32 Klds[2][64][20];          // 16 data u32 + 4 pad (row 80 B)
  __shared__ u32 Vlds[2][32][36];          // 32 data u32 + 4 pad (row 144 B)
  __shared__ unsigned char Mlds[2][64][64];// mask tile, byte-rotated rows
  __shared__ u32 Plds[4][16][36];          // 32 data u32 + 4 pad, per-wave

  const int bid = blockIdx.x;
  const int qt = bid & 31, h = (bid >> 5) & 7, b = bid >> 8;
  const int q0 = qt * 64;
  const int t = threadIdx.x, w = t >> 6, l = t & 63, g = l >> 4, c = l & 15;

  // Q as B-frag (col = q-token = c, k-dim = dh = 8g+j), held in regs
  const bf16x8 qf = asfrag(*(const uint4*)(qb + (size_t)(b * NN + q0 + 16 * w + c) * 256 + h * 32 + 8 * g));
  f32x4 oacc[2] = {};

  const int srowK = t >> 2, ssegK = t & 3;       // K & mask tiles: 64 rows
  const int srowV = t >> 3, ssegV = t & 7;       // V^T tile: 32 rows x 8 16B segs
  const u16* kg = kb + (size_t)(b * 8 + h) * 65536 + srowK * 32 + ssegK * 8;
  const u16* vg = vtb + (size_t)(h * 32 + srowV) * 8192 + (size_t)b * NN + ssegV * 8;
  const unsigned char* mg = m8 + (size_t)(q0 + srowK) * NN + ssegK * 16;

  const int mb0 = (16 * ssegK + 8 * (srowK & 7)) & 63;   // byte-rotation by 8*(row&7)
  const int mb1 = (mb0 + 8) & 63;

  // prologue: stage tile 0
  uint4 krg = *(const uint4*)kg;
  uint4 vrg = *(const uint4*)vg;
  uint4 mrg = *(const uint4*)mg;
  *(uint4*)&Klds[0][srowK][ssegK * 4] = krg;
  *(uint4*)&Vlds[0][srowV][ssegV * 4] = vrg;
  *(uint2*)&Mlds[0][srowK][mb0] = make_uint2(mrg.x, mrg.y);
  *(uint2*)&Mlds[0][srowK][mb1] = make_uint2(mrg.z, mrg.w);
  __syncthreads();

  const f32x4 zf = {0.f, 0.f, 0.f, 0.f};
  u32* Pw = &Plds[w][0][0];          // wave-private, row stride 36 u32

  for (int it = 0; it < 32; ++it) {
    const int cur = it & 1;
    if (it < 31) {                   // prefetch tile it+1 (global; hides under compute)
      const int kt = (it + 1) * 64;
      krg = *(const uint4*)(kg + (size_t)kt * 32);
      vrg = *(const uint4*)(vg + kt);
      mrg = *(const uint4*)(mg + kt);
    }
    // S^T = mfma(K, Q): lane(g,c): q = q0+16w+c, k = kt + 16tt + 4g + r
#pragma unroll
    for (int tt = 0; tt < 4; ++tt) {
      bf16x8 kf = asfrag(*(const uint4*)&Klds[cur][16 * tt + c][4 * g]);
      f32x4 s = __builtin_amdgcn_mfma_f32_16x16x32_bf16(kf, qf, zf, 0, 0, 0);
      u32 mdw = *(const u32*)&Mlds[cur][16 * w + c][(16 * tt + 4 * g + 8 * (c & 7)) & 63];
      float mf0 = (float)(mdw & 0xffu);
      float mf1 = (float)((mdw >> 8) & 0xffu);
      float mf2 = (float)((mdw >> 16) & 0xffu);
      float mf3 = (float)(mdw >> 24);
      // round-1 proven gate: p = mv * sigmoid(s), __expf = v_mul(log2e) + v_exp
      float p0 = mf0 * __builtin_amdgcn_rcpf(1.f + __expf(-s[0]));
      float p1 = mf1 * __builtin_amdgcn_rcpf(1.f + __expf(-s[1]));
      float p2 = mf2 * __builtin_amdgcn_rcpf(1.f + __expf(-s[2]));
      float p3 = mf3 * __builtin_amdgcn_rcpf(1.f + __expf(-s[3]));
      u32 w0, w1;
      asm("v_cvt_pk_bf16_f32 %0, %1, %2" : "=v"(w0) : "v"(p0), "v"(p1));
      asm("v_cvt_pk_bf16_f32 %0, %1, %2" : "=v"(w1) : "v"(p2), "v"(p3));
      *(uint2*)&Pw[c * 36 + 8 * tt + 2 * g] = make_uint2(w0, w1);
    }
    // hard fence on the wave-private P path (rule-18: lgkmcnt + sched_barrier)
    asm volatile("s_waitcnt lgkmcnt(0)" ::: "memory");
    __builtin_amdgcn_sched_barrier(0);
    // PV: O += P @ V
#pragma unroll
    for (int kk = 0; kk < 2; ++kk) {
      bf16x8 pf = asfrag(*(const uint4*)&Pw[c * 36 + 16 * kk + 4 * g]);
#pragma unroll
      for (int d0 = 0; d0 < 2; ++d0) {
        bf16x8 vf = asfrag(*(const uint4*)&Vlds[cur][16 * d0 + c][16 * kk + 4 * g]);
        oacc[d0] = __builtin_amdgcn_mfma_f32_16x16x32_bf16(pf, vf, oacc[d0], 0, 0, 0);
      }
    }
    if (it < 31) {
      *(uint4*)&Klds[cur ^ 1][srowK][ssegK * 4] = krg;
      *(uint4*)&Vlds[cur ^ 1][srowV][ssegV * 4] = vrg;
      *(uint2*)&Mlds[cur ^ 1][srowK][mb0] = make_uint2(mrg.x, mrg.y);
      *(uint2*)&Mlds[cur ^ 1][srowK][mb1] = make_uint2(mrg.z, mrg.w);
    }
    __syncthreads();
  }

  const size_t obase = (size_t)(b * NN + q0 + 16 * w) * 256 + h * 32;
#pragma unroll
  for (int d0 = 0; d0 < 2; ++d0)
#pragma unroll
    for (int r = 0; r < 4; ++r)
      ob[obase + (size_t)(4 * g + r) * 256 + 16 * d0 + c] = bfu(oacc[d0][r]);
}

// ---------------- LayerNorm: wave per row ----------------
template<int WB>
__global__ __launch_bounds__(256) void ln_kernel(const float* y,
    const float* __restrict__ gam, const float* __restrict__ bet,
    float* outf, u16* outb) {
  const int row = blockIdx.x * 4 + (threadIdx.x >> 6);
  const int l = threadIdx.x & 63;
  const float4 v = ((const float4*)(y + (size_t)row * DD))[l];
  float s1 = v.x + v.y + v.z + v.w;
  float s2 = v.x * v.x + v.y * v.y + v.z * v.z + v.w * v.w;
#pragma unroll
  for (int off = 1; off < 64; off <<= 1) {
    s1 += __shfl_xor(s1, off);
    s2 += __shfl_xor(s2, off);
  }
  const float mean = s1 * (1.f / DD);
  const float var = s2 * (1.f / DD) - mean * mean;
  const float inv = rsqrtf(var + 1e-5f);
  const float4 gg = ((const float4*)gam)[l];
  const float4 bb = ((const float4*)bet)[l];
  float o0 = (v.x - mean) * inv * gg.x + bb.x;
  float o1 = (v.y - mean) * inv * gg.y + bb.y;
  float o2 = (v.z - mean) * inv * gg.z + bb.z;
  float o3 = (v.w - mean) * inv * gg.w + bb.w;
  ((float4*)(outf + (size_t)row * DD))[l] = make_float4(o0, o1, o2, o3);
  if (WB) {
    ((ushort4*)(outb + (size_t)row * DD))[l] = make_ushort4(bfu(o0), bfu(o1), bfu(o2), bfu(o3));
  }
}

extern "C" void kernel_launch(void* const* d_in, const int* in_sizes, int n_in,
                              void* d_out, int out_size, void* d_ws, size_t ws_size,
                              hipStream_t stream) {
  const float* qdt   = (const float*)d_in[0];
  const float* boxes = (const float*)d_in[1];
  const int*   mask  = (const int*)d_in[2];
  const float* Wq = (const float*)d_in[3];
  const float* bq = (const float*)d_in[4];
  const float* Wk = (const float*)d_in[5];
  const float* bk = (const float*)d_in[6];
  const float* Wv = (const float*)d_in[7];
  const float* bv = (const float*)d_in[8];
  const float* Wo = (const float*)d_in[9];
  const float* bo = (const float*)d_in[10];
  const float* W1 = (const float*)d_in[11];
  const float* b1 = (const float*)d_in[12];
  const float* W2 = (const float*)d_in[13];
  const float* b2 = (const float*)d_in[14];
  const float* g1  = (const float*)d_in[15];
  const float* be1 = (const float*)d_in[16];
  const float* g2  = (const float*)d_in[17];
  const float* be2 = (const float*)d_in[18];

  char* ws = (char*)d_ws;
  float* x     = (float*)(ws + 0);          // [8192,256] f32 (later reused as y2)
  u16*   xb    = (u16*)  (ws + 8388608);
  u16*   qbuf  = (u16*)  (ws + 12582912);   // q, LAMBDA-scaled
  u16*   kbuf  = (u16*)  (ws + 16777216);   // [B][H][2048][32]
  u16*   vtbuf = (u16*)  (ws + 20971520);   // [256][8192]
  u16*   obuf  = (u16*)  (ws + 25165824);
  float* y1    = (float*)(ws + 29360128);
  u16*   t1b   = (u16*)  (ws + 37748736);
  u16*   f1b   = (u16*)  (ws + 41943040);
  u16*   wqkvT = (u16*)  (ws + 46137344);   // [768,256]
  u16*   woT   = (u16*)  (ws + 46530560);
  u16*   w1T   = (u16*)  (ws + 46661632);
  u16*   w2T   = (u16*)  (ws + 46792704);
  float* bqkv  = (float*)(ws + 46923776);
  unsigned char* m8 = (unsigned char*)(ws + 46926848);  // [2048,2048] u8 (no overlay)

  // merged prep: x/xb (2048 blk) + mask->m8 (4096 blk) + weights (1539 blk)
  prep_kernel<<<7683, 256, 0, stream>>>(qdt, boxes, mask, Wq, Wk, Wv, Wo, W1, W2,
                                        bq, bk, bv, x, xb, m8,
                                        wqkvT, woT, w1T, w2T, bqkv);
  // Q (scaled) + K (relayout): [8192,256] x [256,512]
  gemm_qk_kernel<<<dim3(128, 8), 256, 0, stream>>>(xb, wqkvT, bqkv, qbuf, kbuf);
  // V^T: [256,256] x [256,8192]^T
  gemm_vt_kernel<<<dim3(4, 128), 256, 0, stream>>>(wqkvT + 512 * 256, xb, bqkv + 512, vtbuf);
  // attention
  attn_kernel<<<1024, 256, 0, stream>>>(qbuf, kbuf, vtbuf, m8, obuf);
  // attn_out = O@Wo + bo + x  (fp32)
  gemm256_kernel<2><<<dim3(128, 4), 256, 0, stream>>>(obuf, woT, bo, x, y1, 256);
  // LN1 in-place + bf16 copy
  ln_kernel<1><<<2048, 256, 0, stream>>>(y1, g1, be1, y1, t1b);
  // FF1 + relu
  gemm256_kernel<1><<<dim3(128, 4), 256, 0, stream>>>(t1b, w1T, b1, nullptr, f1b, 256);
  // FF2 + b2 + t1 -> reuse x
  gemm256_kernel<2><<<dim3(128, 4), 256, 0, stream>>>(f1b, w2T, b2, y1, x, 256);
  // LN2 -> d_out
  ln_kernel<0><<<2048, 256, 0, stream>>>(x, g2, be2, (float*)d_out, nullptr);
}